// Round 4
// baseline (150.804 us; speedup 1.0000x reference)
//
#include <hip/hip_runtime.h>
#include <math.h>

#define KS 63
#define RAD 31
#define NB 8
#define NC 3
#define NH 512
#define NW 512
#define PADH 576   // 32 zero rows + 512 + 32 zero rows

struct GaussW { float w[KS]; };

// Horizontal 63-tap blur of (noise*2-1), zero padding, written into a
// row-padded scratch [NB*2, 576, 512] in d_ws (rows 0..31, 544..575 zeroed).
// NOTE (R4): hipLaunchCooperativeKernel fails under the harness's graph
// capture (kernel silently never runs) — keep the multi-dispatch structure.
__global__ __launch_bounds__(256) void hblur_kernel(const float* __restrict__ noise,
                                                    float* __restrict__ tmp, GaussW gw) {
    const int bid = blockIdx.x;
    const int t = threadIdx.x;
    if (bid >= NB * NH) {                      // ---- pad-zero path ----
        const int pid = bid - NB * NH;         // [0, 512)
        const int img = pid >> 5;              // 16 planes
        const int pr  = pid & 31;              // 32 row-pairs per plane
        const int row = (pr < 16) ? (pr * 2) : (544 + (pr - 16) * 2);
        float4* dst = (float4*)(tmp + ((size_t)img * PADH + row) * NW);
        dst[t] = make_float4(0.f, 0.f, 0.f, 0.f);   // 256 * 16B = 2 rows
        return;
    }
    // ---- compute path ----
    const int b = bid >> 9;
    const int h = bid & (NH - 1);
    const int ch = t >> 7;                     // waves 0,1 -> ch0; 2,3 -> ch1
    const int tt = t & 127;

    __shared__ float rows[2][PADH];
    const float* src = noise + ((size_t)(b * 2 + ch) * NH + h) * NW;
    {
        const float4 nv = *(const float4*)(src + 4 * tt);
        float4 sv;
        sv.x = fmaf(nv.x, 2.f, -1.f); sv.y = fmaf(nv.y, 2.f, -1.f);
        sv.z = fmaf(nv.z, 2.f, -1.f); sv.w = fmaf(nv.w, 2.f, -1.f);
        *(float4*)&rows[ch][32 + 4 * tt] = sv;
        if (tt < 8) {
            *(float4*)&rows[ch][4 * tt]       = make_float4(0.f, 0.f, 0.f, 0.f);
            *(float4*)&rows[ch][544 + 4 * tt] = make_float4(0.f, 0.f, 0.f, 0.f);
        }
    }
    __syncthreads();

    float acc[4] = {0.f, 0.f, 0.f, 0.f};
#pragma unroll
    for (int c = 0; c < 17; ++c) {
        const float4 v = *(const float4*)&rows[ch][4 * tt + 4 * c];
        const float vv[4] = {v.x, v.y, v.z, v.w};
#pragma unroll
        for (int e = 0; e < 4; ++e) {
#pragma unroll
            for (int oo = 0; oo < 4; ++oo) {
                const int j = 4 * c + e - oo - 1;   // compile-time tap index
                if (j >= 0 && j < KS) acc[oo] = fmaf(vv[e], gw.w[j], acc[oo]);
            }
        }
    }
    float4* dst = (float4*)(tmp + (((size_t)(b * 2 + ch) * PADH) + 32 + h) * NW + 4 * tt);
    *dst = make_float4(acc[0], acc[1], acc[2], acc[3]);
}

// R8 (this round): split the old fused vwarp. vblur does ONLY the vertical
// 63-tap blur, float4-vectorized along w (4x fewer load instructions for the
// same bytes — the old kernel's 132 scalar loads/thread were the latency
// bottleneck). Thread = 4w x 4h x 2ch. Writes disp (final output) directly,
// 32B contiguous per lane. Tap order identical to R3 (rr ascending, j=rr-o)
// -> bitwise-identical disp.
__global__ __launch_bounds__(256) void vblur_kernel(const float* __restrict__ tmp,
                                                    float2* __restrict__ disp, GaussW gw) {
    const int t = threadIdx.x;
    int bid = blockIdx.x;                      // 512 blocks
    bid = (bid & 7) * 64 + (bid >> 3);         // XCD remap: each XCD owns one batch
    const int b  = bid >> 6;
    const int hb = bid & 63;                   // 64 row-blocks of 8 rows
    const int wq = t & 127;                    // 128 * 4w = 512
    const int rg = t >> 7;                     // 2 row-groups of 4 rows
    const int h0 = hb * 8 + rg * 4;
    const int w4 = wq * 4;

    const float* c0 = tmp + (((size_t)(b * 2 + 0) * PADH) + h0 + 1) * NW + w4;
    const float* c1 = tmp + (((size_t)(b * 2 + 1) * PADH) + h0 + 1) * NW + w4;

    float4 ax[4], ay[4];
#pragma unroll
    for (int o = 0; o < 4; ++o) {
        ax[o] = make_float4(0.f, 0.f, 0.f, 0.f);
        ay[o] = make_float4(0.f, 0.f, 0.f, 0.f);
    }
#pragma unroll
    for (int rr = 0; rr < 66; ++rr) {
        const float4 vx = *(const float4*)(c0 + (size_t)rr * NW);
        const float4 vy = *(const float4*)(c1 + (size_t)rr * NW);
#pragma unroll
        for (int o = 0; o < 4; ++o) {
            const int j = rr - o;              // compile-time tap index
            if (j >= 0 && j < KS) {
                const float wj = gw.w[j];
                ax[o].x = fmaf(vx.x, wj, ax[o].x); ax[o].y = fmaf(vx.y, wj, ax[o].y);
                ax[o].z = fmaf(vx.z, wj, ax[o].z); ax[o].w = fmaf(vx.w, wj, ax[o].w);
                ay[o].x = fmaf(vy.x, wj, ay[o].x); ay[o].y = fmaf(vy.y, wj, ay[o].y);
                ay[o].z = fmaf(vy.z, wj, ay[o].z); ay[o].w = fmaf(vy.w, wj, ay[o].w);
            }
        }
    }
#pragma unroll
    for (int o = 0; o < 4; ++o) {
        float2* row = disp + ((size_t)b * NH + h0 + o) * NW + w4;
        *(float4*)(row)     = make_float4(ax[o].x, ay[o].x, ax[o].y, ay[o].y);
        *(float4*)(row + 2) = make_float4(ax[o].z, ay[o].z, ax[o].w, ay[o].w);
    }
}

// Pure gather kernel: 4 px/thread, tiny register state -> 8192 waves = 32/CU
// supply so the clustered bilinear gathers are hidden by TLP. Reads disp back
// (coalesced float4), math identical to R3's epilogue -> bitwise-same warped.
__global__ __launch_bounds__(256) void warp_kernel(const float* __restrict__ img,
                                                   const float2* __restrict__ disp,
                                                   float* __restrict__ warped) {
    const int t = threadIdx.x;
    int bid = blockIdx.x;                      // 2048 blocks
    bid = (bid & 7) * 256 + (bid >> 3);        // XCD remap: each XCD owns one batch
    const int b   = bid >> 8;
    const int blk = bid & 255;                 // 256 chunks of 1024 px (2 rows)
    const int pix = blk * 1024 + t * 4;        // within-plane px index, 4 px/thread
    const int h  = pix >> 9;
    const int w0 = pix & 511;

    const float2* dp = disp + (size_t)b * NH * NW + pix;
    const float4 dA = *(const float4*)(dp);        // px0 (x,y), px1 (x,y)
    const float4 dB = *(const float4*)(dp + 2);    // px2 (x,y), px3 (x,y)
    const float dx[4] = {dA.x, dA.z, dB.x, dB.z};
    const float dy[4] = {dA.y, dA.w, dB.y, dB.w};

    const float* i0 = img + (size_t)b * NC * NH * NW;
    const float* i1 = i0 + NH * NW;
    const float* i2 = i1 + NH * NW;
    float* wp = warped + (size_t)b * NC * NH * NW + pix;

    const float gy0 = fmaf((float)h, 2.0f / 511.0f, -1.0f);
    float o0[4], o1[4], o2[4];
#pragma unroll
    for (int k = 0; k < 4; ++k) {
        float gx = fmaf((float)(w0 + k), 2.0f / 511.0f, -1.0f) + dx[k];
        float gy = gy0 + dy[k];
        gx = fminf(1.f, fmaxf(-1.f, gx));
        gy = fminf(1.f, fmaxf(-1.f, gy));

        const float x = ((gx + 1.0f) * (float)NW - 1.0f) * 0.5f;
        const float y = ((gy + 1.0f) * (float)NH - 1.0f) * 0.5f;
        const float xf = floorf(x), yf = floorf(y);
        const int x0 = (int)xf, y0 = (int)yf;
        const int x1 = x0 + 1,  y1 = y0 + 1;
        const float wx1 = x - xf, wx0 = 1.0f - wx1;
        const float wy1 = y - yf, wy0 = 1.0f - wy1;
        // validity folded into weights (no divergent conditional loads)
        const float fx0 = ((unsigned)x0 < NW) ? 1.f : 0.f;
        const float fx1 = ((unsigned)x1 < NW) ? 1.f : 0.f;
        const float fy0 = ((unsigned)y0 < NH) ? 1.f : 0.f;
        const float fy1 = ((unsigned)y1 < NH) ? 1.f : 0.f;
        const int x0c = min(max(x0, 0), NW - 1), x1c = min(max(x1, 0), NW - 1);
        const int y0c = min(max(y0, 0), NH - 1), y1c = min(max(y1, 0), NH - 1);
        const float w00 = wy0 * wx0 * (fy0 * fx0), w01 = wy0 * wx1 * (fy0 * fx1);
        const float w10 = wy1 * wx0 * (fy1 * fx0), w11 = wy1 * wx1 * (fy1 * fx1);
        const int o00 = y0c * NW + x0c, o01 = y0c * NW + x1c;
        const int o10 = y1c * NW + x0c, o11 = y1c * NW + x1c;
        o0[k] = ((i0[o00] * w00 + i0[o01] * w01) + i0[o10] * w10) + i0[o11] * w11;
        o1[k] = ((i1[o00] * w00 + i1[o01] * w01) + i1[o10] * w10) + i1[o11] * w11;
        o2[k] = ((i2[o00] * w00 + i2[o01] * w01) + i2[o10] * w10) + i2[o11] * w11;
    }
    *(float4*)(wp)                  = make_float4(o0[0], o0[1], o0[2], o0[3]);
    *(float4*)(wp + NH * NW)        = make_float4(o1[0], o1[1], o1[2], o1[3]);
    *(float4*)(wp + 2 * NH * NW)    = make_float4(o2[0], o2[1], o2[2], o2[3]);
}

extern "C" void kernel_launch(void* const* d_in, const int* in_sizes, int n_in,
                              void* d_out, int out_size, void* d_ws, size_t ws_size,
                              hipStream_t stream) {
    const float* image = (const float*)d_in[0];  // [8,3,512,512] fp32
    const float* noise = (const float*)d_in[1];  // [8,2,512,512] fp32
    float* warped = (float*)d_out;                               // [8,3,512,512]
    float* dispo  = (float*)d_out + (size_t)NB * NC * NH * NW;   // [8,512,512,2]
    float* scratch = (float*)d_ws;   // [NB*2, 576, 512] = 18.9 MB, pad rows re-zeroed each call

    GaussW gw;
    float s = 0.f;
    for (int i = 0; i < KS; ++i) {
        const float xv = (float)(i - RAD);
        gw.w[i] = expf(-(xv * xv) / (2.0f * 32.0f * 32.0f));
        s += gw.w[i];
    }
    for (int i = 0; i < KS; ++i) gw.w[i] /= s;

    hblur_kernel<<<NB * NH + 512, 256, 0, stream>>>(noise, scratch, gw);
    vblur_kernel<<<512, 256, 0, stream>>>(scratch, (float2*)dispo, gw);
    warp_kernel<<<2048, 256, 0, stream>>>(image, (const float2*)dispo, warped);
}

// Round 5
// 138.452 us; speedup vs baseline: 1.0892x; 1.0892x over previous
//
#include <hip/hip_runtime.h>
#include <math.h>

#define KS 63
#define RAD 31
#define NB 8
#define NC 3
#define NH 512
#define NW 512
#define PADH 576   // 32 zero rows + 512 + 32 zero rows
#define TILE_H 16
#define TILE_W 64
#define ROWS 78    // TILE_H + 62 taps-halo

struct GaussW { float w[KS]; };

// Horizontal 63-tap blur of (noise*2-1), zero padding, written into a
// row-padded scratch [NB*2, 576, 512] in d_ws (rows 0..31, 544..575 zeroed).
// NOTE (R4): hipLaunchCooperativeKernel fails under the harness's graph
// capture (kernel silently never runs) — keep the multi-dispatch structure.
__global__ __launch_bounds__(256) void hblur_kernel(const float* __restrict__ noise,
                                                    float* __restrict__ tmp, GaussW gw) {
    const int bid = blockIdx.x;
    const int t = threadIdx.x;
    if (bid >= NB * NH) {                      // ---- pad-zero path ----
        const int pid = bid - NB * NH;         // [0, 512)
        const int img = pid >> 5;              // 16 planes
        const int pr  = pid & 31;              // 32 row-pairs per plane
        const int row = (pr < 16) ? (pr * 2) : (544 + (pr - 16) * 2);
        float4* dst = (float4*)(tmp + ((size_t)img * PADH + row) * NW);
        dst[t] = make_float4(0.f, 0.f, 0.f, 0.f);   // 256 * 16B = 2 rows
        return;
    }
    // ---- compute path ----
    const int b = bid >> 9;
    const int h = bid & (NH - 1);
    const int ch = t >> 7;                     // waves 0,1 -> ch0; 2,3 -> ch1
    const int tt = t & 127;

    __shared__ float rows[2][PADH];
    const float* src = noise + ((size_t)(b * 2 + ch) * NH + h) * NW;
    {
        const float4 nv = *(const float4*)(src + 4 * tt);
        float4 sv;
        sv.x = fmaf(nv.x, 2.f, -1.f); sv.y = fmaf(nv.y, 2.f, -1.f);
        sv.z = fmaf(nv.z, 2.f, -1.f); sv.w = fmaf(nv.w, 2.f, -1.f);
        *(float4*)&rows[ch][32 + 4 * tt] = sv;
        if (tt < 8) {
            *(float4*)&rows[ch][4 * tt]       = make_float4(0.f, 0.f, 0.f, 0.f);
            *(float4*)&rows[ch][544 + 4 * tt] = make_float4(0.f, 0.f, 0.f, 0.f);
        }
    }
    __syncthreads();

    float acc[4] = {0.f, 0.f, 0.f, 0.f};
#pragma unroll
    for (int c = 0; c < 17; ++c) {
        const float4 v = *(const float4*)&rows[ch][4 * tt + 4 * c];
        const float vv[4] = {v.x, v.y, v.z, v.w};
#pragma unroll
        for (int e = 0; e < 4; ++e) {
#pragma unroll
            for (int oo = 0; oo < 4; ++oo) {
                const int j = 4 * c + e - oo - 1;   // compile-time tap index
                if (j >= 0 && j < KS) acc[oo] = fmaf(vv[e], gw.w[j], acc[oo]);
            }
        }
    }
    float4* dst = (float4*)(tmp + (((size_t)(b * 2 + ch) * PADH) + 32 + h) * NW + 4 * tt);
    *dst = make_float4(acc[0], acc[1], acc[2], acc[3]);
}

// Fused vertical blur + grid_sample, R9: LDS row-staged.
// R4-R8 history: fused scalar-load version latency-bound at ~40-56us (132
// scalar global loads/thread); split version (R8) regressed +14.5us (disp
// HBM round-trip + extra dispatch). This version keeps fusion (disp in regs)
// but stages the 78 scratch rows x 64 cols x 2ch tile in 40KB LDS via ~10
// coalesced float4 loads/thread; compute reads are conflict-free ds_read_b32
// (lanes->consecutive banks, 2/bank = free). Vertical redundancy 16.5x->4.9x.
// Tap order identical to R3 (rr ascending, j=rr-o) -> bitwise-same outputs.
__global__ __launch_bounds__(256) void vwarp_kernel(const float* __restrict__ tmp,
                                                    const float* __restrict__ img,
                                                    float2* __restrict__ disp,
                                                    float* __restrict__ warped,
                                                    GaussW gw) {
    const int t = threadIdx.x;
    int bid = blockIdx.x;                      // 2048 blocks
    bid = (bid & 7) * 256 + (bid >> 3);        // XCD remap: each XCD owns one batch
    const int b   = bid >> 8;
    const int rem = bid & 255;
    const int ht  = rem >> 3;                  // 32 h-tiles of 16 rows
    const int wt  = rem & 7;                   // 8 w-tiles of 64 cols
    const int H0 = ht * TILE_H;
    const int W0 = wt * TILE_W;

    __shared__ float lds[2][ROWS][TILE_W];     // 39.9 KB

    // ---- stage: rows H0+1 .. H0+78 of both channels, 64-col slice ----
    const float* g0 = tmp + ((size_t)(b * 2) * PADH + H0 + 1) * NW + W0;
    const size_t choff = (size_t)PADH * NW;
    for (int idx = t; idx < 2 * ROWS * (TILE_W / 4); idx += 256) {  // 2496 float4
        const int l16  = idx & 15;
        const int rowc = idx >> 4;             // 0..155
        const int c = (rowc >= ROWS) ? 1 : 0;
        const int r = rowc - ROWS * c;
        const float4 v = *(const float4*)(g0 + (size_t)c * choff + (size_t)r * NW + l16 * 4);
        *(float4*)&lds[c][r][l16 * 4] = v;
    }
    __syncthreads();

    // ---- vertical blur from LDS: 4 rows/thread ----
    const int w  = t & 63;
    const int lh = (t >> 6) * 4;               // 0,4,8,12

    float ax[4] = {0.f, 0.f, 0.f, 0.f};
    float ay[4] = {0.f, 0.f, 0.f, 0.f};
#pragma unroll
    for (int rr = 0; rr < 66; ++rr) {
        const float vx = lds[0][lh + rr][w];
        const float vy = lds[1][lh + rr][w];
#pragma unroll
        for (int o = 0; o < 4; ++o) {
            const int j = rr - o;              // compile-time tap index
            if (j >= 0 && j < KS) {
                ax[o] = fmaf(vx, gw.w[j], ax[o]);
                ay[o] = fmaf(vy, gw.w[j], ay[o]);
            }
        }
    }

    // ---- epilogue: disp write + bilinear gather (identical math to R3) ----
    const int wg = W0 + w;
    const float gxb = fmaf((float)wg, 2.0f / 511.0f, -1.0f);
    const float* i0 = img + (size_t)b * NC * NH * NW;
    const float* i1 = i0 + NH * NW;
    const float* i2 = i1 + NH * NW;
    float* wp = warped + (size_t)b * NC * NH * NW;

#pragma unroll
    for (int o = 0; o < 4; ++o) {
        const int h = H0 + lh + o;
        disp[((size_t)b * NH + h) * NW + wg] = make_float2(ax[o], ay[o]);

        float gx = gxb + ax[o];
        float gy = fmaf((float)h, 2.0f / 511.0f, -1.0f) + ay[o];
        gx = fminf(1.f, fmaxf(-1.f, gx));
        gy = fminf(1.f, fmaxf(-1.f, gy));

        const float x = ((gx + 1.0f) * (float)NW - 1.0f) * 0.5f;
        const float y = ((gy + 1.0f) * (float)NH - 1.0f) * 0.5f;
        const float xf = floorf(x), yf = floorf(y);
        const int x0 = (int)xf, y0 = (int)yf;
        const int x1 = x0 + 1,  y1 = y0 + 1;
        const float wx1 = x - xf, wx0 = 1.0f - wx1;
        const float wy1 = y - yf, wy0 = 1.0f - wy1;
        // validity folded into weights (no divergent conditional loads)
        const float fx0 = ((unsigned)x0 < NW) ? 1.f : 0.f;
        const float fx1 = ((unsigned)x1 < NW) ? 1.f : 0.f;
        const float fy0 = ((unsigned)y0 < NH) ? 1.f : 0.f;
        const float fy1 = ((unsigned)y1 < NH) ? 1.f : 0.f;
        const int x0c = min(max(x0, 0), NW - 1), x1c = min(max(x1, 0), NW - 1);
        const int y0c = min(max(y0, 0), NH - 1), y1c = min(max(y1, 0), NH - 1);
        const float w00 = wy0 * wx0 * (fy0 * fx0), w01 = wy0 * wx1 * (fy0 * fx1);
        const float w10 = wy1 * wx0 * (fy1 * fx0), w11 = wy1 * wx1 * (fy1 * fx1);
        const int o00 = y0c * NW + x0c, o01 = y0c * NW + x1c;
        const int o10 = y1c * NW + x0c, o11 = y1c * NW + x1c;
        const size_t po = (size_t)h * NW + wg;
        wp[po]               = ((i0[o00] * w00 + i0[o01] * w01) + i0[o10] * w10) + i0[o11] * w11;
        wp[NH * NW + po]     = ((i1[o00] * w00 + i1[o01] * w01) + i1[o10] * w10) + i1[o11] * w11;
        wp[2 * NH * NW + po] = ((i2[o00] * w00 + i2[o01] * w01) + i2[o10] * w10) + i2[o11] * w11;
    }
}

extern "C" void kernel_launch(void* const* d_in, const int* in_sizes, int n_in,
                              void* d_out, int out_size, void* d_ws, size_t ws_size,
                              hipStream_t stream) {
    const float* image = (const float*)d_in[0];  // [8,3,512,512] fp32
    const float* noise = (const float*)d_in[1];  // [8,2,512,512] fp32
    float* warped = (float*)d_out;                               // [8,3,512,512]
    float* dispo  = (float*)d_out + (size_t)NB * NC * NH * NW;   // [8,512,512,2]
    float* scratch = (float*)d_ws;   // [NB*2, 576, 512] = 18.9 MB, pad rows re-zeroed each call

    GaussW gw;
    float s = 0.f;
    for (int i = 0; i < KS; ++i) {
        const float xv = (float)(i - RAD);
        gw.w[i] = expf(-(xv * xv) / (2.0f * 32.0f * 32.0f));
        s += gw.w[i];
    }
    for (int i = 0; i < KS; ++i) gw.w[i] /= s;

    hblur_kernel<<<NB * NH + 512, 256, 0, stream>>>(noise, scratch, gw);
    vwarp_kernel<<<NB * (NH / TILE_H) * (NW / TILE_W), 256, 0, stream>>>(
        scratch, image, (float2*)dispo, warped, gw);
}

// Round 6
// 136.456 us; speedup vs baseline: 1.1051x; 1.0146x over previous
//
#include <hip/hip_runtime.h>
#include <math.h>

#define KS 63
#define RAD 31
#define NB 8
#define NC 3
#define NH 512
#define NW 512
#define PADH 576   // 32 zero rows + 512 + 32 zero rows
#define TILE_H 32
#define TILE_W 32
#define ROWS 94    // TILE_H + 62 taps-halo

struct GaussW { float w[KS]; };

// Horizontal 63-tap blur of (noise*2-1), zero padding, written into a
// row-padded scratch [NB*2, 576, 512] in d_ws (rows 0..31, 544..575 zeroed).
// NOTE (R4): hipLaunchCooperativeKernel fails under the harness's graph
// capture (kernel silently never runs) — keep the multi-dispatch structure.
__global__ __launch_bounds__(256) void hblur_kernel(const float* __restrict__ noise,
                                                    float* __restrict__ tmp, GaussW gw) {
    const int bid = blockIdx.x;
    const int t = threadIdx.x;
    if (bid >= NB * NH) {                      // ---- pad-zero path ----
        const int pid = bid - NB * NH;         // [0, 512)
        const int img = pid >> 5;              // 16 planes
        const int pr  = pid & 31;              // 32 row-pairs per plane
        const int row = (pr < 16) ? (pr * 2) : (544 + (pr - 16) * 2);
        float4* dst = (float4*)(tmp + ((size_t)img * PADH + row) * NW);
        dst[t] = make_float4(0.f, 0.f, 0.f, 0.f);   // 256 * 16B = 2 rows
        return;
    }
    // ---- compute path ----
    const int b = bid >> 9;
    const int h = bid & (NH - 1);
    const int ch = t >> 7;                     // waves 0,1 -> ch0; 2,3 -> ch1
    const int tt = t & 127;

    __shared__ float rows[2][PADH];
    const float* src = noise + ((size_t)(b * 2 + ch) * NH + h) * NW;
    {
        const float4 nv = *(const float4*)(src + 4 * tt);
        float4 sv;
        sv.x = fmaf(nv.x, 2.f, -1.f); sv.y = fmaf(nv.y, 2.f, -1.f);
        sv.z = fmaf(nv.z, 2.f, -1.f); sv.w = fmaf(nv.w, 2.f, -1.f);
        *(float4*)&rows[ch][32 + 4 * tt] = sv;
        if (tt < 8) {
            *(float4*)&rows[ch][4 * tt]       = make_float4(0.f, 0.f, 0.f, 0.f);
            *(float4*)&rows[ch][544 + 4 * tt] = make_float4(0.f, 0.f, 0.f, 0.f);
        }
    }
    __syncthreads();

    float acc[4] = {0.f, 0.f, 0.f, 0.f};
#pragma unroll
    for (int c = 0; c < 17; ++c) {
        const float4 v = *(const float4*)&rows[ch][4 * tt + 4 * c];
        const float vv[4] = {v.x, v.y, v.z, v.w};
#pragma unroll
        for (int e = 0; e < 4; ++e) {
#pragma unroll
            for (int oo = 0; oo < 4; ++oo) {
                const int j = 4 * c + e - oo - 1;   // compile-time tap index
                if (j >= 0 && j < KS) acc[oo] = fmaf(vv[e], gw.w[j], acc[oo]);
            }
        }
    }
    float4* dst = (float4*)(tmp + (((size_t)(b * 2 + ch) * PADH) + 32 + h) * NW + 4 * tt);
    *dst = make_float4(acc[0], acc[1], acc[2], acc[3]);
}

// Fused vertical blur + grid_sample, R10: LDS row-staged, 32x32 tile.
// R9 post-mortem: 16x64 tile = 40KB LDS -> only 4 blocks/CU resident and the
// stage->barrier->compute phases can't overlap across so few blocks; vwarp
// pinned at 42us, Occupancy 22%. This round: 32x32 tile -> ROWS=94, LDS
// 23.5KB -> 6 blocks/CU (144KB<160KB), 24-wave supply, cross-block phase
// overlap. Vertical redundancy 4.9x -> 2.9x. Blur LDS reads: addr=r*32+w,
// lanes 0-31 = banks 0-31, lanes 32-63 alias 2-way = free (m136).
// Tap order identical (rr ascending, j=rr-o) -> bitwise-same outputs.
__global__ __launch_bounds__(256) void vwarp_kernel(const float* __restrict__ tmp,
                                                    const float* __restrict__ img,
                                                    float2* __restrict__ disp,
                                                    float* __restrict__ warped,
                                                    GaussW gw) {
    const int t = threadIdx.x;
    int bid = blockIdx.x;                      // 2048 blocks
    bid = (bid & 7) * 256 + (bid >> 3);        // XCD remap: each XCD owns one batch
    const int b   = bid >> 8;
    const int rem = bid & 255;
    const int ht  = rem >> 4;                  // 16 h-tiles of 32 rows
    const int wt  = rem & 15;                  // 16 w-tiles of 32 cols
    const int H0 = ht * TILE_H;
    const int W0 = wt * TILE_W;

    __shared__ float lds[2][ROWS][TILE_W];     // 23.5 KB -> 6 blocks/CU

    // ---- stage: rows H0+1 .. H0+94 of both channels, 32-col slice ----
    const float* g0 = tmp + ((size_t)(b * 2) * PADH + H0 + 1) * NW + W0;
    const size_t choff = (size_t)PADH * NW;
    for (int idx = t; idx < 2 * ROWS * (TILE_W / 4); idx += 256) {  // 1504 float4
        const int c4   = idx & 7;              // 8 float4 per row
        const int rowc = idx >> 3;             // 0..187
        const int c = (rowc >= ROWS) ? 1 : 0;
        const int r = rowc - ROWS * c;
        const float4 v = *(const float4*)(g0 + (size_t)c * choff + (size_t)r * NW + c4 * 4);
        *(float4*)&lds[c][r][c4 * 4] = v;
    }
    __syncthreads();

    // ---- vertical blur from LDS: 4 rows/thread ----
    const int w  = t & 31;
    const int lh = (t >> 5) * 4;               // 0,4,...,28

    float ax[4] = {0.f, 0.f, 0.f, 0.f};
    float ay[4] = {0.f, 0.f, 0.f, 0.f};
#pragma unroll
    for (int rr = 0; rr < 66; ++rr) {
        const float vx = lds[0][lh + rr][w];
        const float vy = lds[1][lh + rr][w];
#pragma unroll
        for (int o = 0; o < 4; ++o) {
            const int j = rr - o;              // compile-time tap index
            if (j >= 0 && j < KS) {
                ax[o] = fmaf(vx, gw.w[j], ax[o]);
                ay[o] = fmaf(vy, gw.w[j], ay[o]);
            }
        }
    }

    // ---- epilogue: disp write + bilinear gather (identical math to R3) ----
    const int wg = W0 + w;
    const float gxb = fmaf((float)wg, 2.0f / 511.0f, -1.0f);
    const float* i0 = img + (size_t)b * NC * NH * NW;
    const float* i1 = i0 + NH * NW;
    const float* i2 = i1 + NH * NW;
    float* wp = warped + (size_t)b * NC * NH * NW;

#pragma unroll
    for (int o = 0; o < 4; ++o) {
        const int h = H0 + lh + o;
        disp[((size_t)b * NH + h) * NW + wg] = make_float2(ax[o], ay[o]);

        float gx = gxb + ax[o];
        float gy = fmaf((float)h, 2.0f / 511.0f, -1.0f) + ay[o];
        gx = fminf(1.f, fmaxf(-1.f, gx));
        gy = fminf(1.f, fmaxf(-1.f, gy));

        const float x = ((gx + 1.0f) * (float)NW - 1.0f) * 0.5f;
        const float y = ((gy + 1.0f) * (float)NH - 1.0f) * 0.5f;
        const float xf = floorf(x), yf = floorf(y);
        const int x0 = (int)xf, y0 = (int)yf;
        const int x1 = x0 + 1,  y1 = y0 + 1;
        const float wx1 = x - xf, wx0 = 1.0f - wx1;
        const float wy1 = y - yf, wy0 = 1.0f - wy1;
        // validity folded into weights (no divergent conditional loads)
        const float fx0 = ((unsigned)x0 < NW) ? 1.f : 0.f;
        const float fx1 = ((unsigned)x1 < NW) ? 1.f : 0.f;
        const float fy0 = ((unsigned)y0 < NH) ? 1.f : 0.f;
        const float fy1 = ((unsigned)y1 < NH) ? 1.f : 0.f;
        const int x0c = min(max(x0, 0), NW - 1), x1c = min(max(x1, 0), NW - 1);
        const int y0c = min(max(y0, 0), NH - 1), y1c = min(max(y1, 0), NH - 1);
        const float w00 = wy0 * wx0 * (fy0 * fx0), w01 = wy0 * wx1 * (fy0 * fx1);
        const float w10 = wy1 * wx0 * (fy1 * fx0), w11 = wy1 * wx1 * (fy1 * fx1);
        const int o00 = y0c * NW + x0c, o01 = y0c * NW + x1c;
        const int o10 = y1c * NW + x0c, o11 = y1c * NW + x1c;
        const size_t po = (size_t)h * NW + wg;
        wp[po]               = ((i0[o00] * w00 + i0[o01] * w01) + i0[o10] * w10) + i0[o11] * w11;
        wp[NH * NW + po]     = ((i1[o00] * w00 + i1[o01] * w01) + i1[o10] * w10) + i1[o11] * w11;
        wp[2 * NH * NW + po] = ((i2[o00] * w00 + i2[o01] * w01) + i2[o10] * w10) + i2[o11] * w11;
    }
}

extern "C" void kernel_launch(void* const* d_in, const int* in_sizes, int n_in,
                              void* d_out, int out_size, void* d_ws, size_t ws_size,
                              hipStream_t stream) {
    const float* image = (const float*)d_in[0];  // [8,3,512,512] fp32
    const float* noise = (const float*)d_in[1];  // [8,2,512,512] fp32
    float* warped = (float*)d_out;                               // [8,3,512,512]
    float* dispo  = (float*)d_out + (size_t)NB * NC * NH * NW;   // [8,512,512,2]
    float* scratch = (float*)d_ws;   // [NB*2, 576, 512] = 18.9 MB, pad rows re-zeroed each call

    GaussW gw;
    float s = 0.f;
    for (int i = 0; i < KS; ++i) {
        const float xv = (float)(i - RAD);
        gw.w[i] = expf(-(xv * xv) / (2.0f * 32.0f * 32.0f));
        s += gw.w[i];
    }
    for (int i = 0; i < KS; ++i) gw.w[i] /= s;

    hblur_kernel<<<NB * NH + 512, 256, 0, stream>>>(noise, scratch, gw);
    vwarp_kernel<<<NB * (NH / TILE_H) * (NW / TILE_W), 256, 0, stream>>>(
        scratch, image, (float2*)dispo, warped, gw);
}